// Round 4
// baseline (3780.302 us; speedup 1.0000x reference)
//
#include <hip/hip_runtime.h>
#include <math.h>

#define BB 2
#define LL 512
#define HH 768
#define WSP 10
#define KTOP 512
#define NLAB 50
#define EE 2048
#define NSPAN 5120
#define H3 2304
#define NEGVD -1000000000.0

__device__ inline double atomAddD(double* a, double v){
  return __hip_atomic_fetch_add(a, v, __ATOMIC_RELAXED, __HIP_MEMORY_SCOPE_AGENT);
}

// ---------------- bucket edges by label + degree ----------------
__global__ void bucket_kernel(const int* __restrict__ edges, int* __restrict__ offsets,
                              int* __restrict__ sorted, float* __restrict__ deg){
  __shared__ int cnt[NLAB];
  __shared__ int pos[NLAB];
  int t = threadIdx.x;
  if (t < NLAB) cnt[t] = 0;
  __syncthreads();
  for (int i = t; i < BB*EE; i += 256){
    int src = edges[i*3+0], tgt = edges[i*3+1], lab = edges[i*3+2];
    bool ok = (lab != -100) && (src < LL) && (tgt < LL);
    if (ok){
      int lc = min(max(lab,0), NLAB-1);
      atomicAdd(&cnt[lc], 1);
      int b = i / EE;
      int tg = min(max(tgt,0), LL-1);
      atomicAdd(&deg[b*LL + tg], 1.0f);
    }
  }
  __syncthreads();
  if (t == 0){
    int s = 0;
    for (int l = 0; l < NLAB; l++){ offsets[l] = s; pos[l] = s; s += cnt[l]; }
    offsets[NLAB] = s;
  }
  __syncthreads();
  for (int i = t; i < BB*EE; i += 256){
    int src = edges[i*3+0], tgt = edges[i*3+1], lab = edges[i*3+2];
    bool ok = (lab != -100) && (src < LL) && (tgt < LL);
    if (ok){
      int lc = min(max(lab,0), NLAB-1);
      int p = atomicAdd(&pos[lc], 1);
      sorted[p] = i;
    }
  }
}

// ---------------- GCN: per-label NT GEMM (f64 acc), scatter to agg_d ----------------
__global__ __launch_bounds__(256) void gcn_gemm(const float* __restrict__ embeddings,
    const int* __restrict__ edges, const float* __restrict__ gcn_w,
    const float* __restrict__ gcn_b, const int* __restrict__ offsets,
    const int* __restrict__ sorted, double* __restrict__ agg_d){
  int l = blockIdx.y;
  int off = offsets[l];
  int cnt = offsets[l+1] - off;
  int m0 = blockIdx.z * 128;
  if (m0 >= cnt) return;
  int n0 = blockIdx.x * 128;
  __shared__ float As[32][132];
  __shared__ float Bs[32][132];
  __shared__ int rbase[128];
  __shared__ int rtgt[128];
  int t = threadIdx.x;
  if (t < 128){
    int m = m0 + t;
    if (m < cnt){
      int id = sorted[off + m];
      int b = id / EE;
      int src = edges[id*3+0]; src = min(max(src,0), LL-1);
      int tgt = edges[id*3+1]; tgt = min(max(tgt,0), LL-1);
      rbase[t] = (b*LL + src) * HH;
      rtgt[t]  = b*LL + tgt;
    } else { rbase[t] = -1; rtgt[t] = -1; }
  }
  double acc[8][8];
  #pragma unroll
  for (int i=0;i<8;i++)
    #pragma unroll
    for (int j=0;j<8;j++) acc[i][j]=0.0;
  int lr = t >> 3;
  int lk = (t & 7) * 4;
  int tx = t & 15, ty = t >> 4;
  const float* Wl = gcn_w + (size_t)l * HH * HH;
  for (int k0 = 0; k0 < HH; k0 += 32){
    __syncthreads();
    #pragma unroll
    for (int r = 0; r < 4; r++){
      int m = lr + r*32;
      float4 va = make_float4(0.f,0.f,0.f,0.f);
      int rb = rbase[m];
      if (rb >= 0) va = *(const float4*)&embeddings[rb + k0 + lk];
      As[lk+0][m]=va.x; As[lk+1][m]=va.y; As[lk+2][m]=va.z; As[lk+3][m]=va.w;
      float4 vb = *(const float4*)&Wl[(size_t)(n0+m)*HH + k0 + lk];
      Bs[lk+0][m]=vb.x; Bs[lk+1][m]=vb.y; Bs[lk+2][m]=vb.z; Bs[lk+3][m]=vb.w;
    }
    __syncthreads();
    #pragma unroll 4
    for (int k = 0; k < 32; k++){
      float4 a0 = *(const float4*)&As[k][ty*8];
      float4 a1 = *(const float4*)&As[k][ty*8+4];
      float4 bq0 = *(const float4*)&Bs[k][tx*4];
      float4 bq1 = *(const float4*)&Bs[k][64+tx*4];
      double av[8] = {(double)a0.x,(double)a0.y,(double)a0.z,(double)a0.w,
                      (double)a1.x,(double)a1.y,(double)a1.z,(double)a1.w};
      double bv[8] = {(double)bq0.x,(double)bq0.y,(double)bq0.z,(double)bq0.w,
                      (double)bq1.x,(double)bq1.y,(double)bq1.z,(double)bq1.w};
      #pragma unroll
      for (int i=0;i<8;i++)
        #pragma unroll
        for (int j=0;j<8;j++) acc[i][j] = fma(av[i], bv[j], acc[i][j]);
    }
  }
  #pragma unroll
  for (int i=0;i<8;i++){
    int m = ty*8 + i;
    int dst = rtgt[m];
    if (dst < 0) continue;
    #pragma unroll
    for (int j=0;j<8;j++){
      int h = n0 + ((j<4)? tx*4+j : 64+tx*4+(j-4));
      atomAddD(&agg_d[(size_t)dst*HH + h], acc[i][j] + (double)gcn_b[l*HH + h]);
    }
  }
}

// ---------------- emb = embeddings + relu(agg/deg); attn logits (f64) ----------------
__global__ __launch_bounds__(256) void emb_kernel(const float* __restrict__ embeddings,
    const double* __restrict__ agg_d, const float* __restrict__ deg,
    const float* __restrict__ attn_w, const float* __restrict__ attn_b,
    float* __restrict__ emb, double* __restrict__ logits_d){
  int bid = blockIdx.x;
  int t = threadIdx.x;
  double d = (double)fmaxf(deg[bid], 1.0f);
  size_t base = (size_t)bid * HH;
  double part = 0.0;
  #pragma unroll
  for (int c = 0; c < 3; c++){
    int h = t + c*256;
    double g = agg_d[base+h] / d;
    if (g < 0.0) g = 0.0;
    float v = embeddings[base+h] + (float)g;
    emb[base+h] = v;
    part += (double)v * (double)attn_w[h];
  }
  #pragma unroll
  for (int dl = 1; dl < 64; dl <<= 1) part += __shfl_xor(part, dl);
  __shared__ double wred[4];
  if ((t & 63) == 0) wred[t >> 6] = part;
  __syncthreads();
  if (t == 0) logits_d[bid] = wred[0]+wred[1]+wred[2]+wred[3] + (double)attn_b[0];
}

// ---------------- span_rep = [start | end | pooled] (f64 softmax/pool) ----------------
__global__ __launch_bounds__(256) void span_kernel(const float* __restrict__ emb,
    const double* __restrict__ logits_d, float* __restrict__ span_rep){
  int bid = blockIdx.x;
  int b = bid / LL, s = bid % LL;
  int t = threadIdx.x;
  __shared__ float rows[WSP][HH];
  __shared__ double aw[WSP][WSP];
  __shared__ double lg[WSP];
  for (int idx = t; idx < WSP*HH; idx += 256){
    int j = idx / HH, h = idx % HH;
    int r = min(s + j, LL-1);
    rows[j][h] = emb[((size_t)b*LL + r)*HH + h];
  }
  if (t < WSP) lg[t] = logits_d[b*LL + min(s + t, LL-1)];
  __syncthreads();
  if (t < WSP){
    int w = t;
    double mx = -1.0e300;
    for (int j = 0; j <= w; j++) if (s + j < LL) mx = fmax(mx, lg[j]);
    double sum = 0.0;
    for (int j = 0; j < WSP; j++){
      double e = 0.0;
      if (j <= w && s + j < LL) e = exp(lg[j] - mx);
      aw[w][j] = e; sum += e;
    }
    double inv = 1.0 / sum;
    for (int j = 0; j < WSP; j++) aw[w][j] *= inv;
  }
  __syncthreads();
  for (int w = 0; w < WSP; w++){
    size_t obase = ((size_t)b*NSPAN + s*WSP + w) * H3;
    int erow = min(w, LL-1-s);
    #pragma unroll
    for (int c = 0; c < 3; c++){
      int h = t + c*256;
      double pooled = 0.0;
      for (int j = 0; j <= w; j++) pooled = fma(aw[w][j], (double)rows[j][h], pooled);
      span_rep[obase + h]        = rows[0][h];
      span_rep[obase + HH + h]   = rows[erow][h];
      span_rep[obase + 2*HH + h] = (float)pooled;
    }
  }
}

// ---------------- mention MLP: f64-acc GEMM + relu + dot(w2) ----------------
__global__ __launch_bounds__(256) void mlp_gemm(const float* __restrict__ sr,
    const float* __restrict__ w1, const float* __restrict__ b1,
    const float* __restrict__ w2, double* __restrict__ msc){
  int bid = blockIdx.x;                 // 1440 blocks = 80 m x 18 n
  int b2 = (bid & 7) * 180 + (bid >> 3);  // XCD swizzle
  int mb = b2 / 18, nb = b2 % 18;
  int m0 = mb * 128, n0 = nb * 128;
  __shared__ float As[32][132];
  __shared__ float Bs[32][132];
  int t = threadIdx.x;
  double acc[8][8];
  #pragma unroll
  for (int i=0;i<8;i++)
    #pragma unroll
    for (int j=0;j<8;j++) acc[i][j]=0.0;
  int lr = t >> 3;
  int lk = (t & 7) * 4;
  int tx = t & 15, ty = t >> 4;
  for (int k0 = 0; k0 < H3; k0 += 32){
    __syncthreads();
    #pragma unroll
    for (int r = 0; r < 4; r++){
      int m = lr + r*32;
      float4 va = *(const float4*)&sr[(size_t)(m0+m)*H3 + k0 + lk];
      As[lk+0][m]=va.x; As[lk+1][m]=va.y; As[lk+2][m]=va.z; As[lk+3][m]=va.w;
      float4 vb = *(const float4*)&w1[(size_t)(n0+m)*H3 + k0 + lk];
      Bs[lk+0][m]=vb.x; Bs[lk+1][m]=vb.y; Bs[lk+2][m]=vb.z; Bs[lk+3][m]=vb.w;
    }
    __syncthreads();
    #pragma unroll 4
    for (int k = 0; k < 32; k++){
      float4 a0 = *(const float4*)&As[k][ty*8];
      float4 a1 = *(const float4*)&As[k][ty*8+4];
      float4 bq0 = *(const float4*)&Bs[k][tx*4];
      float4 bq1 = *(const float4*)&Bs[k][64+tx*4];
      double av[8] = {(double)a0.x,(double)a0.y,(double)a0.z,(double)a0.w,
                      (double)a1.x,(double)a1.y,(double)a1.z,(double)a1.w};
      double bv[8] = {(double)bq0.x,(double)bq0.y,(double)bq0.z,(double)bq0.w,
                      (double)bq1.x,(double)bq1.y,(double)bq1.z,(double)bq1.w};
      #pragma unroll
      for (int i=0;i<8;i++)
        #pragma unroll
        for (int j=0;j<8;j++) acc[i][j] = fma(av[i], bv[j], acc[i][j]);
    }
  }
  double bbd[8], wwd[8];
  #pragma unroll
  for (int j=0;j<8;j++){
    int h = n0 + ((j<4)? tx*4+j : 64+tx*4+(j-4));
    bbd[j] = (double)b1[h]; wwd[j] = (double)w2[h];
  }
  #pragma unroll
  for (int i=0;i<8;i++){
    double p = 0.0;
    #pragma unroll
    for (int j=0;j<8;j++){
      double hv = acc[i][j] + bbd[j];
      p += (hv > 0.0 ? hv : 0.0) * wwd[j];
    }
    p += __shfl_xor(p, 1); p += __shfl_xor(p, 2);
    p += __shfl_xor(p, 4); p += __shfl_xor(p, 8);
    if (tx == 0) atomAddD(&msc[m0 + ty*8 + i], p);
  }
}

// ---------------- top-k on f64 scores (desc value, asc index ties) ----------------
__global__ __launch_bounds__(1024) void topk_kernel(const double* __restrict__ msc,
    const float* __restrict__ m_b2, int* __restrict__ tidx){
  int b = blockIdx.x;
  int t = threadIdx.x;
  __shared__ double sc[NSPAN];
  __shared__ double wv[16];
  __shared__ int wi[16];
  __shared__ int bwin;
  double b2d = (double)m_b2[0];
  #pragma unroll
  for (int i = 0; i < 5; i++){
    int n = t + i*1024;
    int s = n / WSP, w = n % WSP;
    double v = (s + w < LL) ? (msc[b*NSPAN + n] + b2d) : NEGVD;
    sc[n] = v;
  }
  __syncthreads();
  double lv = sc[t]; int li = t;
  #pragma unroll
  for (int i = 1; i < 5; i++){
    int n = t + i*1024;
    double v = sc[n];
    if (v > lv){ lv = v; li = n; }
  }
  for (int k = 0; k < KTOP; k++){
    double v = lv; int idx = li;
    #pragma unroll
    for (int m = 1; m < 64; m <<= 1){
      double ov = __shfl_xor(v, m);
      int oi = __shfl_xor(idx, m);
      if (ov > v || (ov == v && oi < idx)){ v = ov; idx = oi; }
    }
    if ((t & 63) == 0){ wv[t >> 6] = v; wi[t >> 6] = idx; }
    __syncthreads();
    if (t < 16){
      double v2 = wv[t]; int i2 = wi[t];
      #pragma unroll
      for (int m = 1; m < 16; m <<= 1){
        double ov = __shfl_xor(v2, m);
        int oi = __shfl_xor(i2, m);
        if (ov > v2 || (ov == v2 && oi < i2)){ v2 = ov; i2 = oi; }
      }
      if (t == 0){ tidx[b*KTOP + k] = i2; bwin = i2; }
    }
    __syncthreads();
    int n = bwin;
    if ((n & 1023) == t){
      sc[n] = -1.0e308;
      lv = sc[t]; li = t;
      #pragma unroll
      for (int i = 1; i < 5; i++){
        int nn = t + i*1024;
        double vv = sc[nn];
        if (vv > lv){ lv = vv; li = nn; }
      }
    }
    __syncthreads();
  }
}

// ---------------- pruned dots sa, sb (f64) ----------------
__global__ __launch_bounds__(256) void prune_kernel(const float* __restrict__ span_rep,
    const int* __restrict__ tidx, const float* __restrict__ ant_w,
    double* __restrict__ sa, double* __restrict__ sb){
  int bid = blockIdx.x;                 // b*KTOP + i
  int b = bid / KTOP;
  int t = threadIdx.x;
  int idx = tidx[bid];
  const float* row = span_rep + ((size_t)b*NSPAN + idx) * H3;
  double pa = 0.0, pb = 0.0;
  for (int h = t; h < H3; h += 256){
    double x = (double)row[h];
    pa = fma(x, (double)ant_w[h], pa);
    pb = fma(x, (double)ant_w[H3 + h], pb);
  }
  #pragma unroll
  for (int dl = 1; dl < 64; dl <<= 1){ pa += __shfl_xor(pa, dl); pb += __shfl_xor(pb, dl); }
  __shared__ double ra[4], rb[4];
  if ((t & 63) == 0){ ra[t>>6] = pa; rb[t>>6] = pb; }
  __syncthreads();
  if (t == 0){
    sa[bid] = ra[0]+ra[1]+ra[2]+ra[3];
    sb[bid] = rb[0]+rb[1]+rb[2]+rb[3];
  }
}

// ---------------- final outer sum ----------------
__global__ void final_kernel(const double* __restrict__ sa, const double* __restrict__ sb,
                             const float* __restrict__ ant_b, float* __restrict__ out){
  int o = blockIdx.x*256 + threadIdx.x;
  if (o >= BB*KTOP*KTOP) return;
  int j = o & (KTOP-1);
  int i = (o >> 9) & (KTOP-1);
  int b = o >> 18;
  out[o] = (float)(sb[b*KTOP + i] + sa[b*KTOP + j] + (double)ant_b[0]);
}

extern "C" void kernel_launch(void* const* d_in, const int* in_sizes, int n_in,
                              void* d_out, int out_size, void* d_ws, size_t ws_size,
                              hipStream_t stream) {
  const float* embeddings = (const float*)d_in[0];
  const int*   edges      = (const int*)  d_in[1];
  const float* gcn_w      = (const float*)d_in[2];
  const float* gcn_b      = (const float*)d_in[3];
  const float* attn_w     = (const float*)d_in[4];
  const float* attn_b     = (const float*)d_in[5];
  const float* m_w1       = (const float*)d_in[6];
  const float* m_b1       = (const float*)d_in[7];
  const float* m_w2       = (const float*)d_in[8];
  const float* m_b2       = (const float*)d_in[9];
  const float* ant_w      = (const float*)d_in[10];
  const float* ant_b      = (const float*)d_in[11];
  float* out = (float*)d_out;

  // workspace layout (doubles first for alignment)
  double* agg_d    = (double*)d_ws;                      // 786,432 d
  double* msc_d    = agg_d + (size_t)BB*LL*HH;           // 10,240 d
  float*  deg      = (float*)(msc_d + BB*NSPAN);         // 1,024 f
  double* logits_d = (double*)(deg + BB*LL);             // 1,024 d (4KB offset keeps 8B align)
  double* sa_d     = logits_d + BB*LL;                   // 1,024 d
  double* sb_d     = sa_d + BB*KTOP;                     // 1,024 d
  float*  emb      = (float*)(sb_d + BB*KTOP);           // 786,432 f
  float*  span_rep = emb + (size_t)BB*LL*HH;             // 23,592,960 f
  int*    tki      = (int*)(span_rep + (size_t)BB*NSPAN*H3); // 1,024 i
  int*    offs     = tki + BB*KTOP;                      // 64 i
  int*    sorted   = offs + 64;                          // 4,096 i

  // zero agg_d + msc_d + deg (contiguous)
  hipMemsetAsync(agg_d, 0,
                 (size_t)BB*LL*HH*8 + (size_t)BB*NSPAN*8 + (size_t)BB*LL*4, stream);

  bucket_kernel<<<1, 256, 0, stream>>>(edges, offs, sorted, deg);
  gcn_gemm<<<dim3(HH/128, NLAB, 4), 256, 0, stream>>>(embeddings, edges, gcn_w, gcn_b,
                                                      offs, sorted, agg_d);
  emb_kernel<<<BB*LL, 256, 0, stream>>>(embeddings, agg_d, deg, attn_w, attn_b, emb, logits_d);
  span_kernel<<<BB*LL, 256, 0, stream>>>(emb, logits_d, span_rep);
  mlp_gemm<<<1440, 256, 0, stream>>>(span_rep, m_w1, m_b1, m_w2, msc_d);
  topk_kernel<<<BB, 1024, 0, stream>>>(msc_d, m_b2, tki);
  prune_kernel<<<BB*KTOP, 256, 0, stream>>>(span_rep, tki, ant_w, sa_d, sb_d);
  final_kernel<<<(BB*KTOP*KTOP+255)/256, 256, 0, stream>>>(sa_d, sb_d, ant_b, out);
}